// Round 1
// baseline (512.128 us; speedup 1.0000x reference)
//
#include <hip/hip_runtime.h>

// CompressedLinear: out[M,N] = x[M,K] @ (W_int8[N,K] * scale[N])^T + bias[N]
// M=8192 (B*S), N=4096 (D_OUT), K=4096 (D_IN).
// Strategy: bf16 MFMA GEMM (int8 weights are EXACT in bf16; scale applied in
// epilogue). Reg-staged 2-phase pipeline (conversion forces reg staging),
// XOR-swizzled LDS to kill the 128B-stride bank conflict.

#define BM 128
#define BN 128
#define BK 64

constexpr int Mdim = 8192;
constexpr int Ndim = 4096;
constexpr int Kdim = 4096;
constexpr int KT = Kdim / BK;   // 64 K-iterations

typedef __attribute__((ext_vector_type(8))) short short8;
typedef __attribute__((ext_vector_type(4))) float f32x4;

__device__ __forceinline__ unsigned short f2bf(float f) {
    union { float f; unsigned u; } v; v.f = f;
    unsigned r = v.u + 0x7FFFu + ((v.u >> 16) & 1u);   // round-to-nearest-even
    return (unsigned short)(r >> 16);
}

// swizzled byte offset into a [rows][64] bf16 tile (128 B row stride)
__device__ __forceinline__ int swz(int row, int colbyte) {
    return row * 128 + (colbyte ^ ((row & 7) << 4));
}

__global__ __launch_bounds__(256)
void compressed_linear_gemm(const float* __restrict__ X,
                            const int*   __restrict__ W,
                            const float* __restrict__ scale,
                            const float* __restrict__ bias,
                            float* __restrict__ Out)
{
    __shared__ __align__(16) unsigned short lA[BM * BK];  // 16 KiB
    __shared__ __align__(16) unsigned short lB[BN * BK];  // 16 KiB

    const int tid = threadIdx.x;
    const int bid = blockIdx.x;
    const int tn  = bid & 31;          // N/BN = 32 tiles
    const int tm  = bid >> 5;          // M/BM = 64 tiles
    const int brow = tm * BM;
    const int bcol = tn * BN;

    // staging decomposition: 1024 chunks of 8 elems per tile; 4 chunks/thread
    const int r0 = tid >> 3;           // rows r0, r0+32, r0+64, r0+96
    const int c0 = tid & 7;            // 8-elem chunk within the 64-wide row

    float4 aPre[4][2];
    int4   bPre[4][2];

    auto loadTiles = [&](int t) {
        const int k0 = t * BK;
        #pragma unroll
        for (int i = 0; i < 4; i++) {
            const int row = r0 + 32 * i;
            const float4* pa = reinterpret_cast<const float4*>(
                X + (size_t)(brow + row) * Kdim + k0 + c0 * 8);
            aPre[i][0] = pa[0]; aPre[i][1] = pa[1];
            const int4* pb = reinterpret_cast<const int4*>(
                W + (size_t)(bcol + row) * Kdim + k0 + c0 * 8);
            bPre[i][0] = pb[0]; bPre[i][1] = pb[1];
        }
    };

    auto writeLDS = [&]() {
        #pragma unroll
        for (int i = 0; i < 4; i++) {
            const int row = r0 + 32 * i;
            const int off = swz(row, c0 * 16);
            short8 va, vb;
            va[0] = (short)f2bf(aPre[i][0].x); va[1] = (short)f2bf(aPre[i][0].y);
            va[2] = (short)f2bf(aPre[i][0].z); va[3] = (short)f2bf(aPre[i][0].w);
            va[4] = (short)f2bf(aPre[i][1].x); va[5] = (short)f2bf(aPre[i][1].y);
            va[6] = (short)f2bf(aPre[i][1].z); va[7] = (short)f2bf(aPre[i][1].w);
            // int8 values in [-128,127] are exact in bf16
            vb[0] = (short)f2bf((float)bPre[i][0].x); vb[1] = (short)f2bf((float)bPre[i][0].y);
            vb[2] = (short)f2bf((float)bPre[i][0].z); vb[3] = (short)f2bf((float)bPre[i][0].w);
            vb[4] = (short)f2bf((float)bPre[i][1].x); vb[5] = (short)f2bf((float)bPre[i][1].y);
            vb[6] = (short)f2bf((float)bPre[i][1].z); vb[7] = (short)f2bf((float)bPre[i][1].w);
            *reinterpret_cast<short8*>(reinterpret_cast<char*>(lA) + off) = va;
            *reinterpret_cast<short8*>(reinterpret_cast<char*>(lB) + off) = vb;
        }
    };

    // wave decomposition: 4 waves in 2x2, each owns a 64x64 output sub-tile
    const int lane = tid & 63;
    const int w    = tid >> 6;
    const int wr   = w >> 1;
    const int wc   = w & 1;
    const int fr   = lane & 15;   // A-row / B-col / D-col within fragment
    const int fq   = lane >> 4;   // quadrant: k-offset for A/B, row-group for D

    f32x4 acc[4][4] = {};

    loadTiles(0);

    for (int t = 0; t < KT; t++) {
        writeLDS();
        __syncthreads();
        if (t + 1 < KT) loadTiles(t + 1);   // overlap HBM latency with MFMA

        #pragma unroll
        for (int kk = 0; kk < 2; kk++) {
            short8 af[4], bf[4];
            const int cb = kk * 64 + fq * 16;
            #pragma unroll
            for (int m = 0; m < 4; m++) {
                const int row = wr * 64 + m * 16 + fr;
                af[m] = *reinterpret_cast<const short8*>(
                    reinterpret_cast<const char*>(lA) + swz(row, cb));
            }
            #pragma unroll
            for (int n = 0; n < 4; n++) {
                const int row = wc * 64 + n * 16 + fr;
                bf[n] = *reinterpret_cast<const short8*>(
                    reinterpret_cast<const char*>(lB) + swz(row, cb));
            }
            #pragma unroll
            for (int m = 0; m < 4; m++)
                #pragma unroll
                for (int n = 0; n < 4; n++)
                    acc[m][n] = __builtin_amdgcn_mfma_f32_16x16x32_bf16(
                        af[m], bf[n], acc[m][n], 0, 0, 0);
        }
        __syncthreads();
    }

    // epilogue: dequant scale + bias, fp32 store
    // C/D layout: col = lane&15, row = (lane>>4)*4 + reg  [m89/m91 verified]
    #pragma unroll
    for (int n = 0; n < 4; n++) {
        const int col = bcol + wc * 64 + n * 16 + fr;
        const float sc = scale[col];
        const float bi = bias[col];
        #pragma unroll
        for (int m = 0; m < 4; m++) {
            const int rbase = brow + wr * 64 + m * 16 + fq * 4;
            #pragma unroll
            for (int j = 0; j < 4; j++) {
                Out[(size_t)(rbase + j) * Ndim + col] = acc[m][n][j] * sc + bi;
            }
        }
    }
}

extern "C" void kernel_launch(void* const* d_in, const int* in_sizes, int n_in,
                              void* d_out, int out_size, void* d_ws, size_t ws_size,
                              hipStream_t stream) {
    const float* x     = (const float*)d_in[0];
    const int*   w8    = (const int*)d_in[1];
    const float* scale = (const float*)d_in[2];
    const float* bias  = (const float*)d_in[3];
    float* out = (float*)d_out;

    dim3 grid((Mdim / BM) * (Ndim / BN));   // 64*32 = 2048 blocks
    dim3 block(256);
    compressed_linear_gemm<<<grid, block, 0, stream>>>(x, w8, scale, bias, out);
}

// Round 2
// 400.449 us; speedup vs baseline: 1.2789x; 1.2789x over previous
//
#include <hip/hip_runtime.h>

// CompressedLinear: out[M,N] = x[M,K] @ (W_int8[N,K] * scale[N])^T + bias[N]
// M=8192, N=4096, K=4096.
// Round 2: pre-convert x->bf16 and W->bf16 into d_ws once (removes per-K-tile
// VALU conversion that made round 1 VALU-bound at 56%), then m97-structure
// GEMM: global_load_lds width=16, pre-swizzled global source + swizzled
// ds_read_b128 (rule #21), XCD-aware block swizzle.

#define BM 128
#define BN 128
#define BK 64

constexpr int Mdim = 8192;
constexpr int Ndim = 4096;
constexpr int Kdim = 4096;
constexpr int KT = Kdim / BK;   // 64 K-iterations

typedef __attribute__((ext_vector_type(8))) short short8;
typedef __attribute__((ext_vector_type(4))) float f32x4;
typedef unsigned short ushort_t;

__device__ __forceinline__ unsigned short f2bf(float f) {
    union { float f; unsigned u; } v; v.f = f;
    unsigned r = v.u + 0x7FFFu + ((v.u >> 16) & 1u);   // round-to-nearest-even
    return (unsigned short)(r >> 16);
}

__device__ __forceinline__ void gload_lds16(const void* g, void* l) {
    __builtin_amdgcn_global_load_lds(
        (const __attribute__((address_space(1))) void*)g,
        (__attribute__((address_space(3))) void*)l, 16, 0, 0);
}

// ---------------- conversion kernels (memory-bound, vectorized) -------------

__global__ __launch_bounds__(256)
void cvt_f32_to_bf16(const float* __restrict__ in, ushort_t* __restrict__ out, int n8) {
    int idx = blockIdx.x * blockDim.x + threadIdx.x;
    const int stride = gridDim.x * blockDim.x;
    for (int i = idx; i < n8; i += stride) {
        const float4* p = reinterpret_cast<const float4*>(in + (size_t)i * 8);
        float4 a = p[0], b = p[1];
        short8 v;
        v[0] = (short)f2bf(a.x); v[1] = (short)f2bf(a.y);
        v[2] = (short)f2bf(a.z); v[3] = (short)f2bf(a.w);
        v[4] = (short)f2bf(b.x); v[5] = (short)f2bf(b.y);
        v[6] = (short)f2bf(b.z); v[7] = (short)f2bf(b.w);
        *reinterpret_cast<short8*>(out + (size_t)i * 8) = v;
    }
}

__global__ __launch_bounds__(256)
void cvt_i32_to_bf16(const int* __restrict__ in, ushort_t* __restrict__ out, int n8) {
    int idx = blockIdx.x * blockDim.x + threadIdx.x;
    const int stride = gridDim.x * blockDim.x;
    for (int i = idx; i < n8; i += stride) {
        const int4* p = reinterpret_cast<const int4*>(in + (size_t)i * 8);
        int4 a = p[0], b = p[1];
        short8 v;                                // ints in [-128,127]: exact in bf16
        v[0] = (short)f2bf((float)a.x); v[1] = (short)f2bf((float)a.y);
        v[2] = (short)f2bf((float)a.z); v[3] = (short)f2bf((float)a.w);
        v[4] = (short)f2bf((float)b.x); v[5] = (short)f2bf((float)b.y);
        v[6] = (short)f2bf((float)b.z); v[7] = (short)f2bf((float)b.w);
        *reinterpret_cast<short8*>(out + (size_t)i * 8) = v;
    }
}

// ---------------- main GEMM (m97 structure, bf16 inputs from ws) ------------

__global__ __launch_bounds__(256)
void gemm_bf16_ws(const ushort_t* __restrict__ A,   // [M][K] bf16
                  const ushort_t* __restrict__ B,   // [N][K] bf16
                  const float* __restrict__ scale,
                  const float* __restrict__ bias,
                  float* __restrict__ Out)
{
    __shared__ __align__(16) ushort_t lA[BM * BK];  // 16 KiB, swizzled image
    __shared__ __align__(16) ushort_t lB[BN * BK];  // 16 KiB

    const int tid = threadIdx.x;
    int bid = blockIdx.x;
    bid = (bid & 7) * 256 + (bid >> 3);             // XCD swizzle (2048 % 8 == 0)
    const int tn = bid & 31;                        // N/BN = 32
    const int tm = bid >> 5;                        // M/BM = 64
    const int brow = tm * BM;
    const int bcol = tn * BN;

    const int lane = tid & 63;
    const int w    = tid >> 6;

    // ---- staging addressing (pre-swizzled global source, rule #21) ----
    // LDS byte o = w*4096 + i*1024 + lane*16 holds tile[row][cb] where
    // row = o>>7, cb = (o&127) ^ ((row&7)<<4).  With row = w*32+i*8+(lane>>3):
    // cb = 16*((lane&7) ^ ((lane>>3)&7)).
    const int rsub = lane >> 3;
    const int cswz = ((lane & 7) ^ rsub) << 4;
    const size_t K2 = (size_t)Kdim * 2;             // row stride in bytes
    const char* aSrc = (const char*)A + (size_t)(brow + w * 32 + rsub) * K2 + cswz;
    const char* bSrc = (const char*)B + (size_t)(bcol + w * 32 + rsub) * K2 + cswz;
    char* lAb = (char*)lA + w * 4096;
    char* lBb = (char*)lB + w * 4096;

    // ---- wave / fragment decomposition: 2x2 waves, 64x64 out each ----
    const int wr = w >> 1;
    const int wc = w & 1;
    const int fr = lane & 15;
    const int fq = lane >> 4;

    f32x4 acc[4][4] = {};

    for (int t = 0; t < KT; t++) {
        const size_t koff = (size_t)t * (BK * 2);
        #pragma unroll
        for (int i = 0; i < 4; i++) {
            gload_lds16(aSrc + koff + (size_t)(i * 8) * K2, lAb + i * 1024);
            gload_lds16(bSrc + koff + (size_t)(i * 8) * K2, lBb + i * 1024);
        }
        __syncthreads();   // drains vmcnt(0): staged tiles visible

        #pragma unroll
        for (int kk = 0; kk < 2; kk++) {
            short8 af[4], bfr[4];
            const int cb = kk * 64 + fq * 16;
            #pragma unroll
            for (int m = 0; m < 4; m++) {
                const int row = wr * 64 + m * 16 + fr;
                af[m] = *reinterpret_cast<const short8*>(
                    reinterpret_cast<const char*>(lA) + row * 128 + (cb ^ ((row & 7) << 4)));
            }
            #pragma unroll
            for (int n = 0; n < 4; n++) {
                const int row = wc * 64 + n * 16 + fr;
                bfr[n] = *reinterpret_cast<const short8*>(
                    reinterpret_cast<const char*>(lB) + row * 128 + (cb ^ ((row & 7) << 4)));
            }
            #pragma unroll
            for (int m = 0; m < 4; m++)
                #pragma unroll
                for (int n = 0; n < 4; n++)
                    acc[m][n] = __builtin_amdgcn_mfma_f32_16x16x32_bf16(
                        af[m], bfr[n], acc[m][n], 0, 0, 0);
        }
        __syncthreads();
    }

    // epilogue: dequant scale + bias.  C/D: col=lane&15, row=(lane>>4)*4+reg
    #pragma unroll
    for (int n = 0; n < 4; n++) {
        const int col = bcol + wc * 64 + n * 16 + fr;
        const float sc = scale[col];
        const float bi = bias[col];
        #pragma unroll
        for (int m = 0; m < 4; m++) {
            const int rbase = brow + wr * 64 + m * 16 + fq * 4;
            #pragma unroll
            for (int j = 0; j < 4; j++) {
                Out[(size_t)(rbase + j) * Ndim + col] = acc[m][n][j] * sc + bi;
            }
        }
    }
}

// ---------------- fallback (round-1 kernel) if ws too small -----------------

__device__ __forceinline__ int swz_fb(int row, int colbyte) {
    return row * 128 + (colbyte ^ ((row & 7) << 4));
}

__global__ __launch_bounds__(256)
void compressed_linear_fb(const float* __restrict__ X,
                          const int*   __restrict__ W,
                          const float* __restrict__ scale,
                          const float* __restrict__ bias,
                          float* __restrict__ Out)
{
    __shared__ __align__(16) ushort_t lA[BM * BK];
    __shared__ __align__(16) ushort_t lB[BN * BK];
    const int tid = threadIdx.x;
    const int bid = blockIdx.x;
    const int tn = bid & 31, tm = bid >> 5;
    const int brow = tm * BM, bcol = tn * BN;
    const int r0 = tid >> 3, c0 = tid & 7;
    float4 aPre[4][2]; int4 bPre[4][2];
    const int lane = tid & 63, w = tid >> 6;
    const int wr = w >> 1, wc = w & 1, fr = lane & 15, fq = lane >> 4;
    f32x4 acc[4][4] = {};

    auto loadTiles = [&](int t) {
        const int k0 = t * BK;
        #pragma unroll
        for (int i = 0; i < 4; i++) {
            const int row = r0 + 32 * i;
            const float4* pa = reinterpret_cast<const float4*>(X + (size_t)(brow + row) * Kdim + k0 + c0 * 8);
            aPre[i][0] = pa[0]; aPre[i][1] = pa[1];
            const int4* pb = reinterpret_cast<const int4*>(W + (size_t)(bcol + row) * Kdim + k0 + c0 * 8);
            bPre[i][0] = pb[0]; bPre[i][1] = pb[1];
        }
    };
    auto writeLDS = [&]() {
        #pragma unroll
        for (int i = 0; i < 4; i++) {
            const int row = r0 + 32 * i;
            const int off = swz_fb(row, c0 * 16);
            short8 va, vb;
            va[0] = (short)f2bf(aPre[i][0].x); va[1] = (short)f2bf(aPre[i][0].y);
            va[2] = (short)f2bf(aPre[i][0].z); va[3] = (short)f2bf(aPre[i][0].w);
            va[4] = (short)f2bf(aPre[i][1].x); va[5] = (short)f2bf(aPre[i][1].y);
            va[6] = (short)f2bf(aPre[i][1].z); va[7] = (short)f2bf(aPre[i][1].w);
            vb[0] = (short)f2bf((float)bPre[i][0].x); vb[1] = (short)f2bf((float)bPre[i][0].y);
            vb[2] = (short)f2bf((float)bPre[i][0].z); vb[3] = (short)f2bf((float)bPre[i][0].w);
            vb[4] = (short)f2bf((float)bPre[i][1].x); vb[5] = (short)f2bf((float)bPre[i][1].y);
            vb[6] = (short)f2bf((float)bPre[i][1].z); vb[7] = (short)f2bf((float)bPre[i][1].w);
            *reinterpret_cast<short8*>(reinterpret_cast<char*>(lA) + off) = va;
            *reinterpret_cast<short8*>(reinterpret_cast<char*>(lB) + off) = vb;
        }
    };

    loadTiles(0);
    for (int t = 0; t < KT; t++) {
        writeLDS();
        __syncthreads();
        if (t + 1 < KT) loadTiles(t + 1);
        #pragma unroll
        for (int kk = 0; kk < 2; kk++) {
            short8 af[4], bfr[4];
            const int cb = kk * 64 + fq * 16;
            #pragma unroll
            for (int m = 0; m < 4; m++) {
                const int row = wr * 64 + m * 16 + fr;
                af[m] = *reinterpret_cast<const short8*>(reinterpret_cast<const char*>(lA) + swz_fb(row, cb));
            }
            #pragma unroll
            for (int n = 0; n < 4; n++) {
                const int row = wc * 64 + n * 16 + fr;
                bfr[n] = *reinterpret_cast<const short8*>(reinterpret_cast<const char*>(lB) + swz_fb(row, cb));
            }
            #pragma unroll
            for (int m = 0; m < 4; m++)
                #pragma unroll
                for (int n = 0; n < 4; n++)
                    acc[m][n] = __builtin_amdgcn_mfma_f32_16x16x32_bf16(af[m], bfr[n], acc[m][n], 0, 0, 0);
        }
        __syncthreads();
    }
    #pragma unroll
    for (int n = 0; n < 4; n++) {
        const int col = bcol + wc * 64 + n * 16 + fr;
        const float sc = scale[col];
        const float bi = bias[col];
        #pragma unroll
        for (int m = 0; m < 4; m++) {
            const int rbase = brow + wr * 64 + m * 16 + fq * 4;
            #pragma unroll
            for (int j = 0; j < 4; j++)
                Out[(size_t)(rbase + j) * Ndim + col] = acc[m][n][j] * sc + bi;
        }
    }
}

// ---------------------------------------------------------------------------

extern "C" void kernel_launch(void* const* d_in, const int* in_sizes, int n_in,
                              void* d_out, int out_size, void* d_ws, size_t ws_size,
                              hipStream_t stream) {
    const float* x     = (const float*)d_in[0];
    const int*   w8    = (const int*)d_in[1];
    const float* scale = (const float*)d_in[2];
    const float* bias  = (const float*)d_in[3];
    float* out = (float*)d_out;

    const size_t xbf_bytes = (size_t)Mdim * Kdim * 2;   // 64 MiB
    const size_t wbf_bytes = (size_t)Ndim * Kdim * 2;   // 32 MiB

    dim3 block(256);
    dim3 grid((Mdim / BM) * (Ndim / BN));               // 2048 blocks

    if (ws_size >= xbf_bytes + wbf_bytes) {
        ushort_t* xbf = (ushort_t*)d_ws;
        ushort_t* wbf = (ushort_t*)((char*)d_ws + xbf_bytes);
        cvt_f32_to_bf16<<<2048, 256, 0, stream>>>(x, xbf, (Mdim * Kdim) / 8);
        cvt_i32_to_bf16<<<2048, 256, 0, stream>>>(w8, wbf, (Ndim * Kdim) / 8);
        gemm_bf16_ws<<<grid, block, 0, stream>>>(xbf, wbf, scale, bias, out);
    } else {
        compressed_linear_fb<<<grid, block, 0, stream>>>(x, w8, scale, bias, out);
    }
}

// Round 4
// 275.205 us; speedup vs baseline: 1.8609x; 1.4551x over previous
//
#include <hip/hip_runtime.h>

// CompressedLinear: out = x[8192,4096] @ (W_int8[4096,4096]*scale)^T + bias.
// Round 4: fix round-3 tail race. 256x256 8-phase pipelined GEMM (T2 swizzle +
// T3/T4 counted vmcnt + T5 setprio), bf16 operands pre-converted into d_ws.
//
// Stage/death ledger (phases g0..g7; K-tiles t,t+1 computed; t+2,t+3 staged):
//   g0: stage (t+1).A1 | g1: (t+2).B0 | g2: (t+2).B1 | g3: (t+2).A0 + WAITV4
//   g4: (t+2).A1 | g5: (t+3).B0 | g6: (t+3).B1 | g7: (t+3).A0 + WAITV4
// Steady state: at each WAITV4 the <=4 remaining in-flight ops are next-tile
// halves only. ROUND-3 BUG: in the last iteration no stages are issued, so
// WAITV4 at g3 left (buf1.A0,t+1) and (buf1.A1,t+1) in flight while g4/g6
// read them -> stale last K-tile (absmax 37). FIX: peel the last iteration
// and drain vmcnt(0) at its g3.

#define BM 256
#define BN 256
#define BK 64

constexpr int Mdim = 8192;
constexpr int Ndim = 4096;
constexpr int Kdim = 4096;
constexpr int KT = Kdim / BK;   // 64

typedef __attribute__((ext_vector_type(8))) short short8;
typedef __attribute__((ext_vector_type(4))) float f32x4;
typedef unsigned short ushort_t;

__device__ __forceinline__ unsigned short f2bf(float f) {
    union { float f; unsigned u; } v; v.f = f;
    unsigned r = v.u + 0x7FFFu + ((v.u >> 16) & 1u);
    return (unsigned short)(r >> 16);
}

__device__ __forceinline__ void gload_lds16(const void* g, void* l) {
    __builtin_amdgcn_global_load_lds(
        (const __attribute__((address_space(1))) void*)g,
        (__attribute__((address_space(3))) void*)l, 16, 0, 0);
}

#define BARRIER() __builtin_amdgcn_s_barrier()
#define LGKM0()   asm volatile("s_waitcnt lgkmcnt(0)" ::: "memory")
#define WAITV0()  asm volatile("s_waitcnt vmcnt(0)" ::: "memory")
#define WAITV4()  asm volatile("s_waitcnt vmcnt(4)" ::: "memory")
#define WAITV6()  asm volatile("s_waitcnt vmcnt(6)" ::: "memory")

#define MFMAQ(MH, NH) do {                                                   \
    __builtin_amdgcn_s_setprio(1);                                           \
    _Pragma("unroll") for (int mi = 0; mi < 4; ++mi)                         \
    _Pragma("unroll") for (int ni = 0; ni < 2; ++ni)                         \
    _Pragma("unroll") for (int kk = 0; kk < 2; ++kk)                         \
        acc[(MH)*4+mi][(NH)*2+ni] = __builtin_amdgcn_mfma_f32_16x16x32_bf16( \
            af[mi][kk], bf[(NH)*2+ni][kk], acc[(MH)*4+mi][(NH)*2+ni], 0,0,0);\
    __builtin_amdgcn_s_setprio(0);                                           \
} while (0)

// ---------------- conversion kernels ----------------------------------------

__global__ __launch_bounds__(256)
void cvt_f32_to_bf16(const float* __restrict__ in, ushort_t* __restrict__ out, int n8) {
    int idx = blockIdx.x * blockDim.x + threadIdx.x;
    const int stride = gridDim.x * blockDim.x;
    for (int i = idx; i < n8; i += stride) {
        const float4* p = reinterpret_cast<const float4*>(in + (size_t)i * 8);
        float4 a = p[0], b = p[1];
        short8 v;
        v[0] = (short)f2bf(a.x); v[1] = (short)f2bf(a.y);
        v[2] = (short)f2bf(a.z); v[3] = (short)f2bf(a.w);
        v[4] = (short)f2bf(b.x); v[5] = (short)f2bf(b.y);
        v[6] = (short)f2bf(b.z); v[7] = (short)f2bf(b.w);
        *reinterpret_cast<short8*>(out + (size_t)i * 8) = v;
    }
}

__global__ __launch_bounds__(256)
void cvt_i32_to_bf16(const int* __restrict__ in, ushort_t* __restrict__ out, int n8) {
    int idx = blockIdx.x * blockDim.x + threadIdx.x;
    const int stride = gridDim.x * blockDim.x;
    for (int i = idx; i < n8; i += stride) {
        const int4* p = reinterpret_cast<const int4*>(in + (size_t)i * 8);
        int4 a = p[0], b = p[1];
        short8 v;                         // ints in [-128,127]: exact in bf16
        v[0] = (short)f2bf((float)a.x); v[1] = (short)f2bf((float)a.y);
        v[2] = (short)f2bf((float)a.z); v[3] = (short)f2bf((float)a.w);
        v[4] = (short)f2bf((float)b.x); v[5] = (short)f2bf((float)b.y);
        v[6] = (short)f2bf((float)b.z); v[7] = (short)f2bf((float)b.w);
        *reinterpret_cast<short8*>(out + (size_t)i * 8) = v;
    }
}

// ---------------- 256x256 8-phase GEMM --------------------------------------

__global__ __launch_bounds__(512, 2)
void gemm_bf16_8phase(const ushort_t* __restrict__ A,   // [M][K] bf16
                      const ushort_t* __restrict__ B,   // [N][K] bf16
                      const float* __restrict__ scale,
                      const float* __restrict__ bias,
                      float* __restrict__ Out)
{
    // [buf][half: A0,A1,B0,B1][16 KiB] = 128 KiB
    __shared__ __align__(16) char smem[2][4][16384];

    const int tid = threadIdx.x;
    int bid = blockIdx.x;
    bid = (bid & 7) * 64 + (bid >> 3);          // bijective XCD swizzle (512%8==0)
    const int tn = bid & 15;                    // N/BN = 16
    const int tm = bid >> 4;                    // M/BM = 32
    const int brow = tm * BM;
    const int bcol = tn * BN;

    const int lane = tid & 63;
    const int w    = tid >> 6;                  // 8 waves
    const int wr   = w >> 2;                    // 2 M-waves
    const int wc   = w & 3;                     // 4 N-waves
    const int fr   = lane & 15;
    const int fq   = lane >> 4;
    const size_t K2 = (size_t)Kdim * 2;

    // staging source (pre-swizzled global address; LDS dest stays linear)
    const int swzb = ((lane & 7) ^ (lane >> 3)) << 4;
    const char* aStageSrc = (const char*)A + (size_t)(brow + w * 8 + (lane >> 3)) * K2 + swzb;
    const char* bStageSrc = (const char*)B + (size_t)(bcol + w * 8 + (lane >> 3)) * K2 + swzb;

    auto stageA = [&](int bufb, int h, int tt) {
        const char* s = aStageSrc + (size_t)(h * 128) * K2 + (size_t)tt * 128;
        char* d = &smem[bufb][h][w * 1024];
        gload_lds16(s, d);
        gload_lds16(s + 64 * K2, d + 8192);
    };
    auto stageB = [&](int bufb, int h, int tt) {
        const char* s = bStageSrc + (size_t)(h * 128) * K2 + (size_t)tt * 128;
        char* d = &smem[bufb][2 + h][w * 1024];
        gload_lds16(s, d);
        gload_lds16(s + 64 * K2, d + 8192);
    };

    // ds_read bases (swizzled column bytes)
    const char* aBase[2] = { &smem[0][wr][0] + fr * 128,
                             &smem[1][wr][0] + fr * 128 };
    const char* bBase[2] = { &smem[0][2 + (wc >> 1)][0] + ((wc & 1) * 64 + fr) * 128,
                             &smem[1][2 + (wc >> 1)][0] + ((wc & 1) * 64 + fr) * 128 };
    const int frx   = (fr & 7) << 4;
    const int colb0 = (fq * 16) ^ frx;          // kk=0
    const int colb1 = (64 + fq * 16) ^ frx;     // kk=1

    f32x4 acc[8][4] = {};
    short8 af[4][2], bf[4][2];

    auto ldA = [&](const char* base, int mh) {
        #pragma unroll
        for (int mi = 0; mi < 4; ++mi) {
            const char* p = base + (mh * 4 + mi) * 2048;
            af[mi][0] = *reinterpret_cast<const short8*>(p + colb0);
            af[mi][1] = *reinterpret_cast<const short8*>(p + colb1);
        }
    };
    auto ldB = [&](const char* base) {
        #pragma unroll
        for (int ni = 0; ni < 4; ++ni) {
            const char* p = base + ni * 2048;
            bf[ni][0] = *reinterpret_cast<const short8*>(p + colb0);
            bf[ni][1] = *reinterpret_cast<const short8*>(p + colb1);
        }
    };

    // ---- prologue: t0 full + t1 {B0,B1,A0}; t1's 3 halves may stay in flight
    stageB(0, 0, 0); stageB(0, 1, 0); stageA(0, 0, 0); stageA(0, 1, 0);
    stageB(1, 0, 1); stageB(1, 1, 1); stageA(1, 0, 1);
    WAITV6();          // oldest 8 ops (= all of t0/buf0) landed
    BARRIER();

    // ---- main loop: 31 iterations, all stages unconditional ----
    for (int i = 0; i < KT / 2 - 1; ++i) {
        const int t = 2 * i;

        // g0: q0 of t (buf0)
        ldB(bBase[0]); ldA(aBase[0], 0);
        stageA(1, 1, t + 1);
        BARRIER(); LGKM0();
        MFMAQ(0, 0);
        BARRIER();
        // g1
        stageB(0, 0, t + 2);
        BARRIER(); LGKM0();
        MFMAQ(0, 1);
        BARRIER();
        // g2
        ldA(aBase[0], 1);
        stageB(0, 1, t + 2);
        BARRIER(); LGKM0();
        MFMAQ(1, 0);
        BARRIER();
        // g3 (+ K-tile wait: buf1/t+1 fully landed, <=4 next-tile ops in flight)
        stageA(0, 0, t + 2);
        BARRIER(); LGKM0();
        MFMAQ(1, 1);
        WAITV4();
        BARRIER();
        // g4: q0 of t+1 (buf1)
        ldB(bBase[1]); ldA(aBase[1], 0);
        stageA(0, 1, t + 2);
        BARRIER(); LGKM0();
        MFMAQ(0, 0);
        BARRIER();
        // g5
        stageB(1, 0, t + 3);
        BARRIER(); LGKM0();
        MFMAQ(0, 1);
        BARRIER();
        // g6
        ldA(aBase[1], 1);
        stageB(1, 1, t + 3);
        BARRIER(); LGKM0();
        MFMAQ(1, 0);
        BARRIER();
        // g7 (+ K-tile wait: buf0/t+2 fully landed)
        stageA(1, 0, t + 3);
        BARRIER(); LGKM0();
        MFMAQ(1, 1);
        WAITV4();
        BARRIER();
    }

    // ---- peeled tail: t = KT-2; only stage left is (buf1.A1, t+1).
    //      Full drain at g3 so buf1/t+1 (A0 from prev g7, A1 from g0) is
    //      guaranteed landed before g4/g6 read it.  (the round-3 fix)
    {
        // g0
        ldB(bBase[0]); ldA(aBase[0], 0);
        stageA(1, 1, KT - 1);
        BARRIER(); LGKM0();
        MFMAQ(0, 0);
        BARRIER();
        // g1
        MFMAQ(0, 1);
        BARRIER();
        // g2
        ldA(aBase[0], 1);
        BARRIER(); LGKM0();
        MFMAQ(1, 0);
        BARRIER();
        // g3: drain everything
        MFMAQ(1, 1);
        WAITV0();
        BARRIER();
        // g4
        ldB(bBase[1]); ldA(aBase[1], 0);
        BARRIER(); LGKM0();
        MFMAQ(0, 0);
        // g5
        MFMAQ(0, 1);
        // g6
        ldA(aBase[1], 1);
        LGKM0();
        MFMAQ(1, 0);
        // g7
        MFMAQ(1, 1);
    }

    // epilogue: dequant scale + bias.  C/D: col=lane&15, row=(lane>>4)*4+reg
    #pragma unroll
    for (int n = 0; n < 4; ++n) {
        const int col = bcol + wc * 64 + n * 16 + fr;
        const float sc = scale[col];
        const float bi = bias[col];
        #pragma unroll
        for (int m = 0; m < 8; ++m) {
            const int rbase = brow + wr * 128 + m * 16 + fq * 4;
            #pragma unroll
            for (int j = 0; j < 4; ++j) {
                Out[(size_t)(rbase + j) * Ndim + col] = acc[m][n][j] * sc + bi;
            }
        }
    }
}

// ---------------- fallback (round-1 kernel) if ws too small -----------------

__device__ __forceinline__ int swz_fb(int row, int colbyte) {
    return row * 128 + (colbyte ^ ((row & 7) << 4));
}

__global__ __launch_bounds__(256)
void compressed_linear_fb(const float* __restrict__ X,
                          const int*   __restrict__ W,
                          const float* __restrict__ scale,
                          const float* __restrict__ bias,
                          float* __restrict__ Out)
{
    __shared__ __align__(16) ushort_t lA[128 * 64];
    __shared__ __align__(16) ushort_t lB[128 * 64];
    const int tid = threadIdx.x;
    const int bid = blockIdx.x;
    const int tn = bid & 31, tm = bid >> 5;
    const int brow = tm * 128, bcol = tn * 128;
    const int r0 = tid >> 3, c0 = tid & 7;
    float4 aPre[4][2]; int4 bPre[4][2];
    const int lane = tid & 63, w = tid >> 6;
    const int wr = w >> 1, wc = w & 1, fr = lane & 15, fq = lane >> 4;
    f32x4 acc[4][4] = {};

    auto loadTiles = [&](int t) {
        const int k0 = t * 64;
        #pragma unroll
        for (int i = 0; i < 4; i++) {
            const int row = r0 + 32 * i;
            const float4* pa = reinterpret_cast<const float4*>(X + (size_t)(brow + row) * Kdim + k0 + c0 * 8);
            aPre[i][0] = pa[0]; aPre[i][1] = pa[1];
            const int4* pb = reinterpret_cast<const int4*>(W + (size_t)(bcol + row) * Kdim + k0 + c0 * 8);
            bPre[i][0] = pb[0]; bPre[i][1] = pb[1];
        }
    };
    auto writeLDS = [&]() {
        #pragma unroll
        for (int i = 0; i < 4; i++) {
            const int row = r0 + 32 * i;
            const int off = swz_fb(row, c0 * 16);
            short8 va, vb;
            va[0] = (short)f2bf(aPre[i][0].x); va[1] = (short)f2bf(aPre[i][0].y);
            va[2] = (short)f2bf(aPre[i][0].z); va[3] = (short)f2bf(aPre[i][0].w);
            va[4] = (short)f2bf(aPre[i][1].x); va[5] = (short)f2bf(aPre[i][1].y);
            va[6] = (short)f2bf(aPre[i][1].z); va[7] = (short)f2bf(aPre[i][1].w);
            vb[0] = (short)f2bf((float)bPre[i][0].x); vb[1] = (short)f2bf((float)bPre[i][0].y);
            vb[2] = (short)f2bf((float)bPre[i][0].z); vb[3] = (short)f2bf((float)bPre[i][0].w);
            vb[4] = (short)f2bf((float)bPre[i][1].x); vb[5] = (short)f2bf((float)bPre[i][1].y);
            vb[6] = (short)f2bf((float)bPre[i][1].z); vb[7] = (short)f2bf((float)bPre[i][1].w);
            *reinterpret_cast<short8*>(reinterpret_cast<char*>(lA) + off) = va;
            *reinterpret_cast<short8*>(reinterpret_cast<char*>(lB) + off) = vb;
        }
    };

    loadTiles(0);
    for (int t = 0; t < KT; t++) {
        writeLDS();
        __syncthreads();
        if (t + 1 < KT) loadTiles(t + 1);
        #pragma unroll
        for (int kk = 0; kk < 2; kk++) {
            short8 afv[4], bfv[4];
            const int cb = kk * 64 + fq * 16;
            #pragma unroll
            for (int m = 0; m < 4; m++) {
                const int row = wr * 64 + m * 16 + fr;
                afv[m] = *reinterpret_cast<const short8*>(reinterpret_cast<const char*>(lA) + swz_fb(row, cb));
            }
            #pragma unroll
            for (int n = 0; n < 4; n++) {
                const int row = wc * 64 + n * 16 + fr;
                bfv[n] = *reinterpret_cast<const short8*>(reinterpret_cast<const char*>(lB) + swz_fb(row, cb));
            }
            #pragma unroll
            for (int m = 0; m < 4; m++)
                #pragma unroll
                for (int n = 0; n < 4; n++)
                    acc[m][n] = __builtin_amdgcn_mfma_f32_16x16x32_bf16(afv[m], bfv[n], acc[m][n], 0, 0, 0);
        }
        __syncthreads();
    }
    #pragma unroll
    for (int n = 0; n < 4; n++) {
        const int col = bcol + wc * 64 + n * 16 + fr;
        const float sc = scale[col];
        const float bi = bias[col];
        #pragma unroll
        for (int m = 0; m < 4; m++) {
            const int rbase = brow + wr * 64 + m * 16 + fq * 4;
            #pragma unroll
            for (int j = 0; j < 4; j++)
                Out[(size_t)(rbase + j) * Ndim + col] = acc[m][n][j] * sc + bi;
        }
    }
}

// ---------------------------------------------------------------------------

extern "C" void kernel_launch(void* const* d_in, const int* in_sizes, int n_in,
                              void* d_out, int out_size, void* d_ws, size_t ws_size,
                              hipStream_t stream) {
    const float* x     = (const float*)d_in[0];
    const int*   w8    = (const int*)d_in[1];
    const float* scale = (const float*)d_in[2];
    const float* bias  = (const float*)d_in[3];
    float* out = (float*)d_out;

    const size_t xbf_bytes = (size_t)Mdim * Kdim * 2;   // 64 MiB
    const size_t wbf_bytes = (size_t)Ndim * Kdim * 2;   // 32 MiB

    if (ws_size >= xbf_bytes + wbf_bytes) {
        ushort_t* xbf = (ushort_t*)d_ws;
        ushort_t* wbf = (ushort_t*)((char*)d_ws + xbf_bytes);
        cvt_f32_to_bf16<<<2048, 256, 0, stream>>>(x, xbf, (Mdim * Kdim) / 8);
        cvt_i32_to_bf16<<<2048, 256, 0, stream>>>(w8, wbf, (Ndim * Kdim) / 8);
        dim3 grid((Mdim / BM) * (Ndim / BN));           // 32*16 = 512 blocks
        gemm_bf16_8phase<<<grid, dim3(512), 0, stream>>>(xbf, wbf, scale, bias, out);
    } else {
        dim3 grid((Mdim / 128) * (Ndim / 128));         // 2048 blocks
        compressed_linear_fb<<<grid, dim3(256), 0, stream>>>(x, w8, scale, bias, out);
    }
}